// Round 12
// baseline (498.124 us; speedup 1.0000x reference)
//
#include <hip/hip_runtime.h>
#include <math.h>

#define NHID 64
#define NPB 512          // nodes per bucket (power of two; local id = node & 511)
#define NPB_SHIFT 9
#define MAXB 256         // supports N up to 131072
#define CAP 20480        // entries per bucket region (mean 16384 @ E=3.2M)
#define CHUNK 8192       // edges per k_bucketA chunk

__device__ __forceinline__ float bf_lo(unsigned u) { return __uint_as_float(u << 16); }
__device__ __forceinline__ float bf_hi(unsigned u) { return __uint_as_float(u & 0xffff0000u); }
__device__ __forceinline__ unsigned f2bf(float f) {           // RNE bf16 (top 16 bits)
    unsigned u = __float_as_uint(f);
    return (u + 0x7fffu + ((u >> 16) & 1u)) >> 16;
}

// ---------------------------------------------------------------------------
// K_A: bucketing, one (chunk,side) per block. LDS histogram -> one global
// atomic per (block,bucket) -> rank-scatter of packed (payload<<9|local).
// ---------------------------------------------------------------------------
__global__ __launch_bounds__(256) void k_bucketA(const int* __restrict__ src,
                                                 const int* __restrict__ dst,
                                                 unsigned int* __restrict__ buf0,
                                                 unsigned int* __restrict__ buf1,
                                                 int* __restrict__ btail0,
                                                 int* __restrict__ btail1,
                                                 int E, int nB) {
    int side  = blockIdx.x & 1;
    int chunk = blockIdx.x >> 1;
    const int* key = side ? src : dst;
    const int* pay = side ? dst : src;
    unsigned int* buf = side ? buf1 : buf0;
    int* btail = side ? btail1 : btail0;

    __shared__ int h[MAXB], b[MAXB];
    int tid = threadIdx.x;
    for (int i = tid; i < nB; i += 256) h[i] = 0;
    __syncthreads();
    int e0 = chunk * CHUNK;
    for (int i = tid; i < CHUNK / 4; i += 256) {
        int e = e0 + i * 4;
        if (e + 3 < E) {
            int4 k4 = ((const int4*)(key + e0))[i];
            atomicAdd(&h[k4.x >> NPB_SHIFT], 1);
            atomicAdd(&h[k4.y >> NPB_SHIFT], 1);
            atomicAdd(&h[k4.z >> NPB_SHIFT], 1);
            atomicAdd(&h[k4.w >> NPB_SHIFT], 1);
        } else {
            for (int j = 0; j < 4; ++j) {
                int e2 = e + j;
                if (e2 < E) atomicAdd(&h[key[e2] >> NPB_SHIFT], 1);
            }
        }
    }
    __syncthreads();
    for (int i = tid; i < nB; i += 256) {
        int c = h[i];
        b[i] = c ? atomicAdd(&btail[i], c) : 0;
        h[i] = 0;                    // reuse as rank counter
    }
    __syncthreads();
    for (int i = tid; i < CHUNK / 4; i += 256) {
        int e = e0 + i * 4;
        if (e + 3 < E) {
            int4 k4 = ((const int4*)(key + e0))[i];
            int4 p4 = ((const int4*)(pay + e0))[i];
            int bb, r;
            bb = k4.x >> NPB_SHIFT; r = atomicAdd(&h[bb], 1) + b[bb];
            if (r < CAP) buf[(size_t)bb * CAP + r] = ((unsigned)p4.x << NPB_SHIFT) | (unsigned)(k4.x & (NPB - 1));
            bb = k4.y >> NPB_SHIFT; r = atomicAdd(&h[bb], 1) + b[bb];
            if (r < CAP) buf[(size_t)bb * CAP + r] = ((unsigned)p4.y << NPB_SHIFT) | (unsigned)(k4.y & (NPB - 1));
            bb = k4.z >> NPB_SHIFT; r = atomicAdd(&h[bb], 1) + b[bb];
            if (r < CAP) buf[(size_t)bb * CAP + r] = ((unsigned)p4.z << NPB_SHIFT) | (unsigned)(k4.z & (NPB - 1));
            bb = k4.w >> NPB_SHIFT; r = atomicAdd(&h[bb], 1) + b[bb];
            if (r < CAP) buf[(size_t)bb * CAP + r] = ((unsigned)p4.w << NPB_SHIFT) | (unsigned)(k4.w & (NPB - 1));
        } else {
            for (int j = 0; j < 4; ++j) {
                int e2 = e + j;
                if (e2 < E) {
                    int k = key[e2], p = pay[e2];
                    int bb = k >> NPB_SHIFT;
                    int r = atomicAdd(&h[bb], 1) + b[bb];
                    if (r < CAP) buf[(size_t)bb * CAP + r] = ((unsigned)p << NPB_SHIFT) | (unsigned)(k & (NPB - 1));
                }
            }
        }
    }
}

// ---------------------------------------------------------------------------
// K_B: single-block exclusive scan of per-bucket sizes (both sides).
// ---------------------------------------------------------------------------
__global__ __launch_bounds__(256) void k_bscan(const int* __restrict__ btail0,
                                               const int* __restrict__ btail1,
                                               int* __restrict__ boff0, int* __restrict__ boff1,
                                               int* __restrict__ off0, int* __restrict__ off1,
                                               int nB, int N) {
    __shared__ int sd[256];
    int tid = threadIdx.x;
    int v = (tid < nB) ? min(btail0[tid], CAP) : 0;
    sd[tid] = v; __syncthreads();
    for (int o = 1; o < 256; o <<= 1) {
        int t = (tid >= o) ? sd[tid - o] : 0; __syncthreads();
        sd[tid] += t; __syncthreads();
    }
    if (tid < nB) boff0[tid] = sd[tid] - v;
    if (tid == 255) off0[N] = sd[255];
    __syncthreads();
    v = (tid < nB) ? min(btail1[tid], CAP) : 0;
    sd[tid] = v; __syncthreads();
    for (int o = 1; o < 256; o <<= 1) {
        int t = (tid >= o) ? sd[tid - o] : 0; __syncthreads();
        sd[tid] += t; __syncthreads();
    }
    if (tid < nB) boff1[tid] = sd[tid] - v;
    if (tid == 255) off1[N] = sd[255];
}

// ---------------------------------------------------------------------------
// K_C: per (side,bucket), 512 threads: LDS count -> scan -> off[] -> scatter.
// ---------------------------------------------------------------------------
__global__ __launch_bounds__(512) void k_bucket_csr(const unsigned int* __restrict__ buf0,
                                                    const unsigned int* __restrict__ buf1,
                                                    const int* __restrict__ btail0,
                                                    const int* __restrict__ btail1,
                                                    const int* __restrict__ boff0,
                                                    const int* __restrict__ boff1,
                                                    int* __restrict__ off0, int* __restrict__ off1,
                                                    int* __restrict__ csr0, int* __restrict__ csr1,
                                                    int N) {
    int side = blockIdx.x & 1;
    int b = blockIdx.x >> 1;
    const unsigned int* buf = (side ? buf1 : buf0) + (size_t)b * CAP;
    int cnt_b = min((side ? btail1 : btail0)[b], CAP);
    int boff  = (side ? boff1 : boff0)[b];
    int* off  = side ? off1 : off0;
    int* csr  = side ? csr1 : csr0;
    __shared__ int cnt[NPB];
    __shared__ int scn[NPB];
    __shared__ int cur[NPB];
    int tid = threadIdx.x;          // blockDim == NPB == 512
    cnt[tid] = 0;
    __syncthreads();
    for (int i = tid; i < cnt_b; i += 512)
        atomicAdd(&cnt[buf[i] & (NPB - 1)], 1);
    __syncthreads();
    int v = cnt[tid];
    scn[tid] = v; __syncthreads();
    for (int o = 1; o < 512; o <<= 1) {
        int t = (tid >= o) ? scn[tid - o] : 0; __syncthreads();
        scn[tid] += t; __syncthreads();
    }
    int base = boff + scn[tid] - v;   // exclusive
    cur[tid] = base;
    int node = (b << NPB_SHIFT) + tid;
    if (node < N) off[node] = base;
    __syncthreads();
    for (int i = tid; i < cnt_b; i += 512) {
        unsigned int u = buf[i];
        int pos = atomicAdd(&cur[u & (NPB - 1)], 1);
        csr[pos] = (int)(u >> NPB_SHIFT);
    }
}

// ---------------------------------------------------------------------------
// K_X: pack X (f32) -> Xb, PART-SPLIT layout [4][N][16] bf16 (3.2MB parts).
// ---------------------------------------------------------------------------
__global__ __launch_bounds__(256) void k_xcast(const float* __restrict__ X,
                                               unsigned* __restrict__ Xb, int N) {
    int i = blockIdx.x * 256 + threadIdx.x;
    if (i >= N * 4) return;
    int n = i >> 2, p = i & 3;
    const float4* Xv = (const float4*)(X + (size_t)n * NHID + p * 16);
    float4 f0 = Xv[0], f1 = Xv[1], f2 = Xv[2], f3 = Xv[3];
    uint4 a, c;
    a.x = f2bf(f0.x) | (f2bf(f0.y) << 16);
    a.y = f2bf(f0.z) | (f2bf(f0.w) << 16);
    a.z = f2bf(f1.x) | (f2bf(f1.y) << 16);
    a.w = f2bf(f1.z) | (f2bf(f1.w) << 16);
    c.x = f2bf(f2.x) | (f2bf(f2.y) << 16);
    c.y = f2bf(f2.z) | (f2bf(f2.w) << 16);
    c.z = f2bf(f3.x) | (f2bf(f3.y) << 16);
    c.w = f2bf(f3.z) | (f2bf(f3.w) << 16);
    uint4* d = (uint4*)Xb + ((size_t)p * N + n) * 2;
    d[0] = a; d[1] = c;
}

// ---------------------------------------------------------------------------
// K4p: one feature-part pass of agg = mean over in-edges of X[src].
// Table slice = 3.2MB -> L2-resident. Wave = 16 edge-groups x 4 lanes.
// ---------------------------------------------------------------------------
__global__ __launch_bounds__(256) void k_agg_p(const unsigned* __restrict__ Xbp,
                                               const int* __restrict__ off_dst,
                                               const int* __restrict__ csr_dst,
                                               float* __restrict__ agg, int N, int part) {
    int lane = threadIdx.x & 63;
    int node = blockIdx.x * 4 + (threadIdx.x >> 6);
    if (node >= N) return;
    int grp = lane >> 2, col4 = lane & 3;     // 16 groups x 4 lanes
    const uint2* T = (const uint2*)Xbp;       // row m -> T[m*4 + col4]
    int s0 = off_dst[node], s1 = off_dst[node + 1];
    float4 acc = make_float4(0.f, 0.f, 0.f, 0.f);
    for (int base = s0; base < s1; base += 64) {
        int cnt = min(64, s1 - base);
        int idx = (base + lane < s1) ? csr_dst[base + lane] : 0;
        int j = 0;
        for (; j + 32 <= cnt; j += 32) {
            int m0 = __shfl(idx, j + grp);
            int m1 = __shfl(idx, j + 16 + grp);
            uint2 u0 = T[(size_t)m0 * 4 + col4];
            uint2 u1 = T[(size_t)m1 * 4 + col4];
            acc.x += bf_lo(u0.x); acc.y += bf_hi(u0.x);
            acc.z += bf_lo(u0.y); acc.w += bf_hi(u0.y);
            acc.x += bf_lo(u1.x); acc.y += bf_hi(u1.x);
            acc.z += bf_lo(u1.y); acc.w += bf_hi(u1.y);
        }
        if (j < cnt) {
            int q0 = j + grp, q1 = j + 16 + grp;
            int m0 = __shfl(idx, q0);
            int m1 = __shfl(idx, q1);
            float f0 = (q0 < cnt) ? 1.f : 0.f; if (q0 >= cnt) m0 = 0;
            float f1 = (q1 < cnt) ? 1.f : 0.f; if (q1 >= cnt) m1 = 0;
            uint2 u0 = T[(size_t)m0 * 4 + col4];
            uint2 u1 = T[(size_t)m1 * 4 + col4];
            acc.x += f0 * bf_lo(u0.x); acc.y += f0 * bf_hi(u0.x);
            acc.z += f0 * bf_lo(u0.y); acc.w += f0 * bf_hi(u0.y);
            acc.x += f1 * bf_lo(u1.x); acc.y += f1 * bf_hi(u1.x);
            acc.z += f1 * bf_lo(u1.y); acc.w += f1 * bf_hi(u1.y);
        }
    }
    #pragma unroll
    for (int d = 4; d < 64; d <<= 1) {
        acc.x += __shfl_xor(acc.x, d); acc.y += __shfl_xor(acc.y, d);
        acc.z += __shfl_xor(acc.z, d); acc.w += __shfl_xor(acc.w, d);
    }
    if (grp == 0) {
        int deg = s1 - s0;
        float inv = 1.f / (float)max(deg, 1);
        ((float4*)agg)[(size_t)node * 16 + part * 4 + col4] =
            make_float4(acc.x * inv, acc.y * inv, acc.z * inv, acc.w * inv);
    }
}

// ---------------------------------------------------------------------------
// K5a: X2 = relu(X·Wself + agg·Wneigh + b). Weights in LDS; 4 threads/node.
// Output X2b is PACKED BF16 [N][64] (feeds phaseB).
// ---------------------------------------------------------------------------
__global__ __launch_bounds__(256) void k_phaseA(const float* __restrict__ X,
                                                const float* __restrict__ agg,
                                                const float* __restrict__ Ws,
                                                const float* __restrict__ Wn,
                                                const float* __restrict__ bconv,
                                                unsigned* __restrict__ X2b, int N) {
    __shared__ float sWs[4096];
    __shared__ float sWn[4096];
    __shared__ float sb[64];
    int tid = threadIdx.x;
    for (int i = tid; i < 4096; i += 256) {
        sWs[i] = Ws[i];
        sWn[i] = Wn[i];
    }
    if (tid < 64) sb[tid] = bconv[tid];
    __syncthreads();

    int n = blockIdx.x * 64 + (tid >> 2);
    if (n >= N) return;
    int wb = (tid & 3) << 2;
    const float4* ws4 = (const float4*)sWs;
    const float4* wn4 = (const float4*)sWn;
    const float4* bv  = (const float4*)sb;
    const float4* Xv  = (const float4*)(X + (size_t)n * NHID);
    const float4* Gv  = (const float4*)(agg + (size_t)n * NHID);
    float4 a0 = bv[wb], a1 = bv[wb + 1], a2 = bv[wb + 2], a3 = bv[wb + 3];
    #pragma unroll 2
    for (int q = 0; q < 16; ++q) {
        float4 xq = Xv[q];
        float4 gq = Gv[q];
        float xs[4] = {xq.x, xq.y, xq.z, xq.w};
        float gs[4] = {gq.x, gq.y, gq.z, gq.w};
        #pragma unroll
        for (int j = 0; j < 4; ++j) {
            int k16 = (4 * q + j) * 16 + wb;
            float4 w0 = ws4[k16], w1 = ws4[k16 + 1], w2 = ws4[k16 + 2], w3 = ws4[k16 + 3];
            float4 m0 = wn4[k16], m1 = wn4[k16 + 1], m2 = wn4[k16 + 2], m3 = wn4[k16 + 3];
            float xj = xs[j], gj = gs[j];
            a0.x += xj * w0.x + gj * m0.x; a0.y += xj * w0.y + gj * m0.y;
            a0.z += xj * w0.z + gj * m0.z; a0.w += xj * w0.w + gj * m0.w;
            a1.x += xj * w1.x + gj * m1.x; a1.y += xj * w1.y + gj * m1.y;
            a1.z += xj * w1.z + gj * m1.z; a1.w += xj * w1.w + gj * m1.w;
            a2.x += xj * w2.x + gj * m2.x; a2.y += xj * w2.y + gj * m2.y;
            a2.z += xj * w2.z + gj * m2.z; a2.w += xj * w2.w + gj * m2.w;
            a3.x += xj * w3.x + gj * m3.x; a3.y += xj * w3.y + gj * m3.y;
            a3.z += xj * w3.z + gj * m3.z; a3.w += xj * w3.w + gj * m3.w;
        }
    }
    a0.x = fmaxf(a0.x, 0.f); a0.y = fmaxf(a0.y, 0.f); a0.z = fmaxf(a0.z, 0.f); a0.w = fmaxf(a0.w, 0.f);
    a1.x = fmaxf(a1.x, 0.f); a1.y = fmaxf(a1.y, 0.f); a1.z = fmaxf(a1.z, 0.f); a1.w = fmaxf(a1.w, 0.f);
    a2.x = fmaxf(a2.x, 0.f); a2.y = fmaxf(a2.y, 0.f); a2.z = fmaxf(a2.z, 0.f); a2.w = fmaxf(a2.w, 0.f);
    a3.x = fmaxf(a3.x, 0.f); a3.y = fmaxf(a3.y, 0.f); a3.z = fmaxf(a3.z, 0.f); a3.w = fmaxf(a3.w, 0.f);
    uint4 p0, p1;
    p0.x = f2bf(a0.x) | (f2bf(a0.y) << 16);
    p0.y = f2bf(a0.z) | (f2bf(a0.w) << 16);
    p0.z = f2bf(a1.x) | (f2bf(a1.y) << 16);
    p0.w = f2bf(a1.z) | (f2bf(a1.w) << 16);
    p1.x = f2bf(a2.x) | (f2bf(a2.y) << 16);
    p1.y = f2bf(a2.z) | (f2bf(a2.w) << 16);
    p1.z = f2bf(a3.x) | (f2bf(a3.y) << 16);
    p1.w = f2bf(a3.z) | (f2bf(a3.w) << 16);
    uint4* outp = (uint4*)X2b + (size_t)n * 8 + (tid & 3) * 2;
    outp[0] = p0; outp[1] = p1;
}

// ---------------------------------------------------------------------------
// K_rp: one-shot repack of Qw into W2[64][128] = [A|B] row-major.
// ---------------------------------------------------------------------------
__global__ __launch_bounds__(256) void k_repackB(const float* __restrict__ Qw,
                                                 float* __restrict__ W2) {
    int i = blockIdx.x * 256 + threadIdx.x;   // grid covers 8192
    if (i >= 8192) return;
    int f = i >> 7, c = i & 127;
    float v;
    if (c < 64) v = Qw[(c >> 4) * 2048 + f * 16 + (c & 15)];
    else { int cc = c - 64; v = Qw[(cc >> 4) * 2048 + (64 + f) * 16 + (cc & 15)]; }
    W2[i] = v;
}

// ---------------------------------------------------------------------------
// K5b: [a|b] = X2 · W2 (+[Qb|0]). W2 in LDS. 8 threads/node.
// Outputs written bf16 in PART-SPLIT layout [4][N][16] each.
// ---------------------------------------------------------------------------
__global__ __launch_bounds__(256) void k_phaseB(const unsigned* __restrict__ X2b,
                                                const float* __restrict__ W2,
                                                const float* __restrict__ Qb,
                                                unsigned* __restrict__ aOut,
                                                unsigned* __restrict__ bOut, int N) {
    __shared__ float sW[8192];
    int tid = threadIdx.x;
    for (int i = tid; i < 8192; i += 256) sW[i] = W2[i];
    __syncthreads();

    int n = blockIdx.x * 32 + (tid >> 3);
    if (n >= N) return;
    int part = tid & 7;                 // 0..3 -> a parts, 4..7 -> b parts
    int wb = part << 2;                 // float4 base within 32-float4 row
    const float4* w4 = (const float4*)sW;
    float4 a0, a1, a2, a3;
    if (part < 4) {
        const float4* qv = (const float4*)Qb;
        a0 = qv[wb]; a1 = qv[wb + 1]; a2 = qv[wb + 2]; a3 = qv[wb + 3];
    } else {
        a0 = a1 = a2 = a3 = make_float4(0.f, 0.f, 0.f, 0.f);
    }
    const uint4* Xv = (const uint4*)X2b + (size_t)n * 8;
    #pragma unroll 2
    for (int q8 = 0; q8 < 8; ++q8) {
        uint4 xu = Xv[q8];
        float xs[8] = {bf_lo(xu.x), bf_hi(xu.x), bf_lo(xu.y), bf_hi(xu.y),
                       bf_lo(xu.z), bf_hi(xu.z), bf_lo(xu.w), bf_hi(xu.w)};
        #pragma unroll
        for (int j = 0; j < 8; ++j) {
            int f32b = (8 * q8 + j) * 32 + wb;
            float4 w0 = w4[f32b], w1 = w4[f32b + 1], w2 = w4[f32b + 2], w3 = w4[f32b + 3];
            float xj = xs[j];
            a0.x += xj * w0.x; a0.y += xj * w0.y; a0.z += xj * w0.z; a0.w += xj * w0.w;
            a1.x += xj * w1.x; a1.y += xj * w1.y; a1.z += xj * w1.z; a1.w += xj * w1.w;
            a2.x += xj * w2.x; a2.y += xj * w2.y; a2.z += xj * w2.z; a2.w += xj * w2.w;
            a3.x += xj * w3.x; a3.y += xj * w3.y; a3.z += xj * w3.z; a3.w += xj * w3.w;
        }
    }
    uint4 p0, p1;
    p0.x = f2bf(a0.x) | (f2bf(a0.y) << 16);
    p0.y = f2bf(a0.z) | (f2bf(a0.w) << 16);
    p0.z = f2bf(a1.x) | (f2bf(a1.y) << 16);
    p0.w = f2bf(a1.z) | (f2bf(a1.w) << 16);
    p1.x = f2bf(a2.x) | (f2bf(a2.y) << 16);
    p1.y = f2bf(a2.z) | (f2bf(a2.w) << 16);
    p1.z = f2bf(a3.x) | (f2bf(a3.y) << 16);
    p1.w = f2bf(a3.z) | (f2bf(a3.w) << 16);
    uint4* outp = (part < 4) ? (uint4*)aOut + ((size_t)part * N + n) * 2
                             : (uint4*)bOut + ((size_t)(part - 4) * N + n) * 2;
    outp[0] = p0; outp[1] = p1;
}

// ---------------------------------------------------------------------------
// K6p: one feature-part pass of gg = tanh(mean over out-edges of (a+b_d)^2).
// b part-slice (3.2MB) L2-resident; same 16x4 structure as K4p.
// ---------------------------------------------------------------------------
__global__ __launch_bounds__(256) void k_final_p(const unsigned* __restrict__ aFb,
                                                 const unsigned* __restrict__ bFb,
                                                 const int* __restrict__ off_src,
                                                 const int* __restrict__ csr_src,
                                                 float* __restrict__ out, int N, int part) {
    int lane = threadIdx.x & 63;
    int node = blockIdx.x * 4 + (threadIdx.x >> 6);
    if (node >= N) return;
    int grp = lane >> 2, col4 = lane & 3;     // 16 groups x 4 lanes
    // part slice = N rows x 4 uint2  (FIX: was N*2 -> read garbage for parts 1-3)
    const uint2* T = (const uint2*)bFb + (size_t)part * N * 4;
    uint2 au = ((const uint2*)aFb)[((size_t)part * N + node) * 4 + col4];
    float4 av = make_float4(bf_lo(au.x), bf_hi(au.x), bf_lo(au.y), bf_hi(au.y));
    int s0 = off_src[node], s1 = off_src[node + 1];
    float4 acc = make_float4(0.f, 0.f, 0.f, 0.f);
    for (int base = s0; base < s1; base += 64) {
        int cnt = min(64, s1 - base);
        int idx = (base + lane < s1) ? csr_src[base + lane] : 0;
        int j = 0;
        for (; j + 32 <= cnt; j += 32) {
            int m0 = __shfl(idx, j + grp);
            int m1 = __shfl(idx, j + 16 + grp);
            uint2 u0 = T[(size_t)m0 * 4 + col4];
            uint2 u1 = T[(size_t)m1 * 4 + col4];
            float t;
            t = av.x + bf_lo(u0.x); acc.x += t * t;
            t = av.y + bf_hi(u0.x); acc.y += t * t;
            t = av.z + bf_lo(u0.y); acc.z += t * t;
            t = av.w + bf_hi(u0.y); acc.w += t * t;
            t = av.x + bf_lo(u1.x); acc.x += t * t;
            t = av.y + bf_hi(u1.x); acc.y += t * t;
            t = av.z + bf_lo(u1.y); acc.z += t * t;
            t = av.w + bf_hi(u1.y); acc.w += t * t;
        }
        if (j < cnt) {
            int q0 = j + grp, q1 = j + 16 + grp;
            int m0 = __shfl(idx, q0);
            int m1 = __shfl(idx, q1);
            float f0 = (q0 < cnt) ? 1.f : 0.f; if (q0 >= cnt) m0 = 0;
            float f1 = (q1 < cnt) ? 1.f : 0.f; if (q1 >= cnt) m1 = 0;
            uint2 u0 = T[(size_t)m0 * 4 + col4];
            uint2 u1 = T[(size_t)m1 * 4 + col4];
            float t;
            t = av.x + bf_lo(u0.x); acc.x += f0 * t * t;
            t = av.y + bf_hi(u0.x); acc.y += f0 * t * t;
            t = av.z + bf_lo(u0.y); acc.z += f0 * t * t;
            t = av.w + bf_hi(u0.y); acc.w += f0 * t * t;
            t = av.x + bf_lo(u1.x); acc.x += f1 * t * t;
            t = av.y + bf_hi(u1.x); acc.y += f1 * t * t;
            t = av.z + bf_lo(u1.y); acc.z += f1 * t * t;
            t = av.w + bf_hi(u1.y); acc.w += f1 * t * t;
        }
    }
    #pragma unroll
    for (int d = 4; d < 64; d <<= 1) {
        acc.x += __shfl_xor(acc.x, d); acc.y += __shfl_xor(acc.y, d);
        acc.z += __shfl_xor(acc.z, d); acc.w += __shfl_xor(acc.w, d);
    }
    if (grp == 0) {
        int deg = s1 - s0;
        float inv = 1.f / (float)max(deg, 1);
        ((float4*)out)[(size_t)node * 16 + part * 4 + col4] =
            make_float4(tanhf(acc.x * inv), tanhf(acc.y * inv),
                        tanhf(acc.z * inv), tanhf(acc.w * inv));
    }
}

// ---------------------------------------------------------------------------
extern "C" void kernel_launch(void* const* d_in, const int* in_sizes, int n_in,
                              void* d_out, int out_size, void* d_ws, size_t ws_size,
                              hipStream_t stream) {
    const float* X      = (const float*)d_in[0];
    const int*   ei     = (const int*)d_in[1];
    const float* Wself  = (const float*)d_in[2];
    const float* Wneigh = (const float*)d_in[3];
    const float* bconv  = (const float*)d_in[4];
    const float* Qw     = (const float*)d_in[5];
    const float* Qb     = (const float*)d_in[6];

    int N = in_sizes[0] / NHID;
    int E = in_sizes[1] / 2;
    const int* src = ei;        // edge_index[0]
    const int* dst = ei + E;    // edge_index[1]
    int nB = (N + NPB - 1) >> NPB_SHIFT;           // 196 for N=100K
    int nChunks = (E + CHUNK - 1) / CHUNK;         // 391 for E=3.2M

    // ---- workspace layout (~103 MB) ----
    char* ws = (char*)d_ws;
    size_t bufBytes = (size_t)MAXB * CAP * 4;      // 21.0 MB per side
    size_t NH4 = (size_t)N * NHID * 4;             // 25.6 MB
    size_t NH2 = (size_t)N * NHID * 2;             // 12.8 MB
    unsigned int* buf0 = (unsigned int*)(ws);
    unsigned int* buf1 = (unsigned int*)(ws + bufBytes);
    float*    aggF = (float*)(ws);                              // [0, 25.6)
    unsigned* X2b  = (unsigned*)(ws + NH4);                     // [25.6, 38.4)
    unsigned* aFb  = (unsigned*)(ws + NH4 + NH2);               // [38.4, 51.2) part-split
    unsigned* bFb  = (unsigned*)(ws + NH4 + 2 * NH2);           // [51.2, 64.0) part-split
    unsigned* Xb   = (unsigned*)(ws + NH4 + 3 * NH2);           // [64.0, 76.8) part-split
    size_t pos = NH4 + 4 * NH2;                                 // 76.8 MB
    if (pos < 2 * bufBytes) pos = 2 * bufBytes;
    pos = (pos + 255) & ~(size_t)255;
    auto alloc = [&](size_t bytes) -> void* {
        void* p = ws + pos;
        pos = (pos + bytes + 255) & ~(size_t)255;
        return p;
    };
    int* csr0   = (int*)alloc((size_t)E * 4);      // by dst
    int* csr1   = (int*)alloc((size_t)E * 4);      // by src
    int* off0   = (int*)alloc((size_t)(N + 1) * 4);
    int* off1   = (int*)alloc((size_t)(N + 1) * 4);
    int* btail0 = (int*)alloc((size_t)MAXB * 4);
    int* btail1 = (int*)alloc((size_t)MAXB * 4);
    int* boff0  = (int*)alloc((size_t)MAXB * 4);
    int* boff1  = (int*)alloc((size_t)MAXB * 4);
    float* W2   = (float*)alloc((size_t)8192 * 4); // repacked [A|B], 32KB
    (void)ws_size; (void)n_in; (void)out_size;

    hipMemsetAsync(btail0, 0, (size_t)2 * MAXB * 4, stream);   // btail0+btail1 contiguous

    k_bucketA<<<nChunks * 2, 256, 0, stream>>>(src, dst, buf0, buf1, btail0, btail1, E, nB);
    k_bscan<<<1, 256, 0, stream>>>(btail0, btail1, boff0, boff1, off0, off1, nB, N);
    k_repackB<<<32, 256, 0, stream>>>(Qw, W2);
    k_xcast<<<(N * 4 + 255) / 256, 256, 0, stream>>>(X, Xb, N);
    k_bucket_csr<<<nB * 2, 512, 0, stream>>>(buf0, buf1, btail0, btail1,
                                             boff0, boff1, off0, off1, csr0, csr1, N);
    for (int p = 0; p < 4; ++p)
        k_agg_p<<<(N + 3) / 4, 256, 0, stream>>>(Xb + (size_t)p * N * 8, off0, csr0,
                                                 aggF, N, p);
    k_phaseA<<<(N + 63) / 64, 256, 0, stream>>>(X, aggF, Wself, Wneigh, bconv, X2b, N);
    k_phaseB<<<(N + 31) / 32, 256, 0, stream>>>(X2b, W2, Qb, aFb, bFb, N);
    for (int p = 0; p < 4; ++p)
        k_final_p<<<(N + 3) / 4, 256, 0, stream>>>(aFb, bFb, off1, csr1,
                                                   (float*)d_out, N, p);
}

// Round 13
// 320.494 us; speedup vs baseline: 1.5542x; 1.5542x over previous
//
#include <hip/hip_runtime.h>
#include <math.h>

#define NHID 64
#define NPB 512          // nodes per bucket (power of two; local id = node & 511)
#define NPB_SHIFT 9
#define MAXB 256         // supports N up to 131072
#define CAP 20480        // entries per bucket region (mean 16384 @ E=3.2M)
#define CHUNK 8192       // edges per k_bucketA chunk

__device__ __forceinline__ float bf_lo(unsigned u) { return __uint_as_float(u << 16); }
__device__ __forceinline__ float bf_hi(unsigned u) { return __uint_as_float(u & 0xffff0000u); }
__device__ __forceinline__ unsigned f2bf(float f) {           // RNE bf16 (top 16 bits)
    unsigned u = __float_as_uint(f);
    return (u + 0x7fffu + ((u >> 16) & 1u)) >> 16;
}

// ---------------------------------------------------------------------------
// K_A: bucketing, one (chunk,side) per block. LDS histogram -> one global
// atomic per (block,bucket) -> rank-scatter of packed (payload<<9|local).
// ---------------------------------------------------------------------------
__global__ __launch_bounds__(256) void k_bucketA(const int* __restrict__ src,
                                                 const int* __restrict__ dst,
                                                 unsigned int* __restrict__ buf0,
                                                 unsigned int* __restrict__ buf1,
                                                 int* __restrict__ btail0,
                                                 int* __restrict__ btail1,
                                                 int E, int nB) {
    int side  = blockIdx.x & 1;
    int chunk = blockIdx.x >> 1;
    const int* key = side ? src : dst;
    const int* pay = side ? dst : src;
    unsigned int* buf = side ? buf1 : buf0;
    int* btail = side ? btail1 : btail0;

    __shared__ int h[MAXB], b[MAXB];
    int tid = threadIdx.x;
    for (int i = tid; i < nB; i += 256) h[i] = 0;
    __syncthreads();
    int e0 = chunk * CHUNK;
    for (int i = tid; i < CHUNK / 4; i += 256) {
        int e = e0 + i * 4;
        if (e + 3 < E) {
            int4 k4 = ((const int4*)(key + e0))[i];
            atomicAdd(&h[k4.x >> NPB_SHIFT], 1);
            atomicAdd(&h[k4.y >> NPB_SHIFT], 1);
            atomicAdd(&h[k4.z >> NPB_SHIFT], 1);
            atomicAdd(&h[k4.w >> NPB_SHIFT], 1);
        } else {
            for (int j = 0; j < 4; ++j) {
                int e2 = e + j;
                if (e2 < E) atomicAdd(&h[key[e2] >> NPB_SHIFT], 1);
            }
        }
    }
    __syncthreads();
    for (int i = tid; i < nB; i += 256) {
        int c = h[i];
        b[i] = c ? atomicAdd(&btail[i], c) : 0;
        h[i] = 0;                    // reuse as rank counter
    }
    __syncthreads();
    for (int i = tid; i < CHUNK / 4; i += 256) {
        int e = e0 + i * 4;
        if (e + 3 < E) {
            int4 k4 = ((const int4*)(key + e0))[i];
            int4 p4 = ((const int4*)(pay + e0))[i];
            int bb, r;
            bb = k4.x >> NPB_SHIFT; r = atomicAdd(&h[bb], 1) + b[bb];
            if (r < CAP) buf[(size_t)bb * CAP + r] = ((unsigned)p4.x << NPB_SHIFT) | (unsigned)(k4.x & (NPB - 1));
            bb = k4.y >> NPB_SHIFT; r = atomicAdd(&h[bb], 1) + b[bb];
            if (r < CAP) buf[(size_t)bb * CAP + r] = ((unsigned)p4.y << NPB_SHIFT) | (unsigned)(k4.y & (NPB - 1));
            bb = k4.z >> NPB_SHIFT; r = atomicAdd(&h[bb], 1) + b[bb];
            if (r < CAP) buf[(size_t)bb * CAP + r] = ((unsigned)p4.z << NPB_SHIFT) | (unsigned)(k4.z & (NPB - 1));
            bb = k4.w >> NPB_SHIFT; r = atomicAdd(&h[bb], 1) + b[bb];
            if (r < CAP) buf[(size_t)bb * CAP + r] = ((unsigned)p4.w << NPB_SHIFT) | (unsigned)(k4.w & (NPB - 1));
        } else {
            for (int j = 0; j < 4; ++j) {
                int e2 = e + j;
                if (e2 < E) {
                    int k = key[e2], p = pay[e2];
                    int bb = k >> NPB_SHIFT;
                    int r = atomicAdd(&h[bb], 1) + b[bb];
                    if (r < CAP) buf[(size_t)bb * CAP + r] = ((unsigned)p << NPB_SHIFT) | (unsigned)(k & (NPB - 1));
                }
            }
        }
    }
}

// ---------------------------------------------------------------------------
// K_B: single-block exclusive scan of per-bucket sizes (both sides).
// ---------------------------------------------------------------------------
__global__ __launch_bounds__(256) void k_bscan(const int* __restrict__ btail0,
                                               const int* __restrict__ btail1,
                                               int* __restrict__ boff0, int* __restrict__ boff1,
                                               int* __restrict__ off0, int* __restrict__ off1,
                                               int nB, int N) {
    __shared__ int sd[256];
    int tid = threadIdx.x;
    int v = (tid < nB) ? min(btail0[tid], CAP) : 0;
    sd[tid] = v; __syncthreads();
    for (int o = 1; o < 256; o <<= 1) {
        int t = (tid >= o) ? sd[tid - o] : 0; __syncthreads();
        sd[tid] += t; __syncthreads();
    }
    if (tid < nB) boff0[tid] = sd[tid] - v;
    if (tid == 255) off0[N] = sd[255];
    __syncthreads();
    v = (tid < nB) ? min(btail1[tid], CAP) : 0;
    sd[tid] = v; __syncthreads();
    for (int o = 1; o < 256; o <<= 1) {
        int t = (tid >= o) ? sd[tid - o] : 0; __syncthreads();
        sd[tid] += t; __syncthreads();
    }
    if (tid < nB) boff1[tid] = sd[tid] - v;
    if (tid == 255) off1[N] = sd[255];
}

// ---------------------------------------------------------------------------
// K_C: per (side,bucket), 512 threads: LDS count -> scan -> off[] -> scatter.
// ---------------------------------------------------------------------------
__global__ __launch_bounds__(512) void k_bucket_csr(const unsigned int* __restrict__ buf0,
                                                    const unsigned int* __restrict__ buf1,
                                                    const int* __restrict__ btail0,
                                                    const int* __restrict__ btail1,
                                                    const int* __restrict__ boff0,
                                                    const int* __restrict__ boff1,
                                                    int* __restrict__ off0, int* __restrict__ off1,
                                                    int* __restrict__ csr0, int* __restrict__ csr1,
                                                    int N) {
    int side = blockIdx.x & 1;
    int b = blockIdx.x >> 1;
    const unsigned int* buf = (side ? buf1 : buf0) + (size_t)b * CAP;
    int cnt_b = min((side ? btail1 : btail0)[b], CAP);
    int boff  = (side ? boff1 : boff0)[b];
    int* off  = side ? off1 : off0;
    int* csr  = side ? csr1 : csr0;
    __shared__ int cnt[NPB];
    __shared__ int scn[NPB];
    __shared__ int cur[NPB];
    int tid = threadIdx.x;          // blockDim == NPB == 512
    cnt[tid] = 0;
    __syncthreads();
    for (int i = tid; i < cnt_b; i += 512)
        atomicAdd(&cnt[buf[i] & (NPB - 1)], 1);
    __syncthreads();
    int v = cnt[tid];
    scn[tid] = v; __syncthreads();
    for (int o = 1; o < 512; o <<= 1) {
        int t = (tid >= o) ? scn[tid - o] : 0; __syncthreads();
        scn[tid] += t; __syncthreads();
    }
    int base = boff + scn[tid] - v;   // exclusive
    cur[tid] = base;
    int node = (b << NPB_SHIFT) + tid;
    if (node < N) off[node] = base;
    __syncthreads();
    for (int i = tid; i < cnt_b; i += 512) {
        unsigned int u = buf[i];
        int pos = atomicAdd(&cur[u & (NPB - 1)], 1);
        csr[pos] = (int)(u >> NPB_SHIFT);
    }
}

// ---------------------------------------------------------------------------
// K_X: pack X (f32) -> Xb (bf16 rows [N][64], 128B = 1 line). 8 vals/thread.
// ---------------------------------------------------------------------------
__global__ __launch_bounds__(256) void k_xcast(const float* __restrict__ X,
                                               unsigned* __restrict__ Xb, int total8) {
    int i = blockIdx.x * 256 + threadIdx.x;
    if (i >= total8) return;
    const float4* Xv = (const float4*)X;
    float4 f0 = Xv[(size_t)i * 2];
    float4 f1 = Xv[(size_t)i * 2 + 1];
    uint4 p;
    p.x = f2bf(f0.x) | (f2bf(f0.y) << 16);
    p.y = f2bf(f0.z) | (f2bf(f0.w) << 16);
    p.z = f2bf(f1.x) | (f2bf(f1.y) << 16);
    p.w = f2bf(f1.z) | (f2bf(f1.w) << 16);
    ((uint4*)Xb)[i] = p;
}

// ---------------------------------------------------------------------------
// K4: agg[n,:] = mean over in-edges of Xb[src,:] (bf16 rows, 128B = 1 line).
// Wave = 8 edge-groups x 8 lanes; 32 edges/iter = 4 dwordx4 loads in flight.
// ---------------------------------------------------------------------------
#define AGG_ACC(u) \
    accA.x += bf_lo(u.x); accA.y += bf_hi(u.x); \
    accA.z += bf_lo(u.y); accA.w += bf_hi(u.y); \
    accB.x += bf_lo(u.z); accB.y += bf_hi(u.z); \
    accB.z += bf_lo(u.w); accB.w += bf_hi(u.w);
#define AGG_ACCM(u, f) \
    accA.x += f * bf_lo(u.x); accA.y += f * bf_hi(u.x); \
    accA.z += f * bf_lo(u.y); accA.w += f * bf_hi(u.y); \
    accB.x += f * bf_lo(u.z); accB.y += f * bf_hi(u.z); \
    accB.z += f * bf_lo(u.w); accB.w += f * bf_hi(u.w);

__global__ __launch_bounds__(256) void k_agg(const unsigned* __restrict__ Xb,
                                             const int* __restrict__ off_dst,
                                             const int* __restrict__ csr_dst,
                                             float* __restrict__ agg, int N) {
    int lane = threadIdx.x & 63;
    int node = blockIdx.x * 4 + (threadIdx.x >> 6);
    if (node >= N) return;
    int grp = lane >> 3, col8 = lane & 7;
    const uint4* Xb4 = (const uint4*)Xb;          // row n -> Xb4[n*8 + col8]
    int s0 = off_dst[node], s1 = off_dst[node + 1];
    float4 accA = make_float4(0.f, 0.f, 0.f, 0.f);
    float4 accB = make_float4(0.f, 0.f, 0.f, 0.f);
    for (int base = s0; base < s1; base += 64) {
        int cnt = min(64, s1 - base);
        int idx = (base + lane < s1) ? csr_dst[base + lane] : 0;
        int j = 0;
        for (; j + 32 <= cnt; j += 32) {
            int m0 = __shfl(idx, j + grp);
            int m1 = __shfl(idx, j + 8 + grp);
            int m2 = __shfl(idx, j + 16 + grp);
            int m3 = __shfl(idx, j + 24 + grp);
            uint4 u0 = Xb4[(size_t)m0 * 8 + col8];
            uint4 u1 = Xb4[(size_t)m1 * 8 + col8];
            uint4 u2 = Xb4[(size_t)m2 * 8 + col8];
            uint4 u3 = Xb4[(size_t)m3 * 8 + col8];
            AGG_ACC(u0); AGG_ACC(u1); AGG_ACC(u2); AGG_ACC(u3);
        }
        if (j < cnt) {
            int q0 = j + grp, q1 = j + 8 + grp, q2 = j + 16 + grp, q3 = j + 24 + grp;
            int m0 = __shfl(idx, q0);
            int m1 = __shfl(idx, q1);
            int m2 = __shfl(idx, q2);
            int m3 = __shfl(idx, q3);
            float f0 = (q0 < cnt) ? 1.f : 0.f; if (q0 >= cnt) m0 = 0;
            float f1 = (q1 < cnt) ? 1.f : 0.f; if (q1 >= cnt) m1 = 0;
            float f2 = (q2 < cnt) ? 1.f : 0.f; if (q2 >= cnt) m2 = 0;
            float f3 = (q3 < cnt) ? 1.f : 0.f; if (q3 >= cnt) m3 = 0;
            uint4 u0 = Xb4[(size_t)m0 * 8 + col8];
            uint4 u1 = Xb4[(size_t)m1 * 8 + col8];
            uint4 u2 = Xb4[(size_t)m2 * 8 + col8];
            uint4 u3 = Xb4[(size_t)m3 * 8 + col8];
            AGG_ACCM(u0, f0); AGG_ACCM(u1, f1); AGG_ACCM(u2, f2); AGG_ACCM(u3, f3);
        }
    }
    #pragma unroll
    for (int d = 8; d < 64; d <<= 1) {
        accA.x += __shfl_xor(accA.x, d); accA.y += __shfl_xor(accA.y, d);
        accA.z += __shfl_xor(accA.z, d); accA.w += __shfl_xor(accA.w, d);
        accB.x += __shfl_xor(accB.x, d); accB.y += __shfl_xor(accB.y, d);
        accB.z += __shfl_xor(accB.z, d); accB.w += __shfl_xor(accB.w, d);
    }
    if (grp == 0) {
        int deg = s1 - s0;
        float inv = 1.f / (float)max(deg, 1);
        float4 r0 = make_float4(accA.x * inv, accA.y * inv, accA.z * inv, accA.w * inv);
        float4 r1 = make_float4(accB.x * inv, accB.y * inv, accB.z * inv, accB.w * inv);
        ((float4*)agg)[(size_t)node * 16 + col8 * 2]     = r0;
        ((float4*)agg)[(size_t)node * 16 + col8 * 2 + 1] = r1;
    }
}

// ---------------------------------------------------------------------------
// K5a: X2 = relu(X·Wself + agg·Wneigh + b). Weights in LDS; 4 threads/node.
// Output X2b is PACKED BF16 [N][64] (feeds phaseB). (2-way LDS alias = free.)
// ---------------------------------------------------------------------------
__global__ __launch_bounds__(256) void k_phaseA(const float* __restrict__ X,
                                                const float* __restrict__ agg,
                                                const float* __restrict__ Ws,
                                                const float* __restrict__ Wn,
                                                const float* __restrict__ bconv,
                                                unsigned* __restrict__ X2b, int N) {
    __shared__ float sWs[4096];
    __shared__ float sWn[4096];
    __shared__ float sb[64];
    int tid = threadIdx.x;
    for (int i = tid; i < 4096; i += 256) {
        sWs[i] = Ws[i];
        sWn[i] = Wn[i];
    }
    if (tid < 64) sb[tid] = bconv[tid];
    __syncthreads();

    int n = blockIdx.x * 64 + (tid >> 2);
    if (n >= N) return;
    int wb = (tid & 3) << 2;
    const float4* ws4 = (const float4*)sWs;
    const float4* wn4 = (const float4*)sWn;
    const float4* bv  = (const float4*)sb;
    const float4* Xv  = (const float4*)(X + (size_t)n * NHID);
    const float4* Gv  = (const float4*)(agg + (size_t)n * NHID);
    float4 a0 = bv[wb], a1 = bv[wb + 1], a2 = bv[wb + 2], a3 = bv[wb + 3];
    #pragma unroll 2
    for (int q = 0; q < 16; ++q) {
        float4 xq = Xv[q];
        float4 gq = Gv[q];
        float xs[4] = {xq.x, xq.y, xq.z, xq.w};
        float gs[4] = {gq.x, gq.y, gq.z, gq.w};
        #pragma unroll
        for (int j = 0; j < 4; ++j) {
            int k16 = (4 * q + j) * 16 + wb;
            float4 w0 = ws4[k16], w1 = ws4[k16 + 1], w2 = ws4[k16 + 2], w3 = ws4[k16 + 3];
            float4 m0 = wn4[k16], m1 = wn4[k16 + 1], m2 = wn4[k16 + 2], m3 = wn4[k16 + 3];
            float xj = xs[j], gj = gs[j];
            a0.x += xj * w0.x + gj * m0.x; a0.y += xj * w0.y + gj * m0.y;
            a0.z += xj * w0.z + gj * m0.z; a0.w += xj * w0.w + gj * m0.w;
            a1.x += xj * w1.x + gj * m1.x; a1.y += xj * w1.y + gj * m1.y;
            a1.z += xj * w1.z + gj * m1.z; a1.w += xj * w1.w + gj * m1.w;
            a2.x += xj * w2.x + gj * m2.x; a2.y += xj * w2.y + gj * m2.y;
            a2.z += xj * w2.z + gj * m2.z; a2.w += xj * w2.w + gj * m2.w;
            a3.x += xj * w3.x + gj * m3.x; a3.y += xj * w3.y + gj * m3.y;
            a3.z += xj * w3.z + gj * m3.z; a3.w += xj * w3.w + gj * m3.w;
        }
    }
    a0.x = fmaxf(a0.x, 0.f); a0.y = fmaxf(a0.y, 0.f); a0.z = fmaxf(a0.z, 0.f); a0.w = fmaxf(a0.w, 0.f);
    a1.x = fmaxf(a1.x, 0.f); a1.y = fmaxf(a1.y, 0.f); a1.z = fmaxf(a1.z, 0.f); a1.w = fmaxf(a1.w, 0.f);
    a2.x = fmaxf(a2.x, 0.f); a2.y = fmaxf(a2.y, 0.f); a2.z = fmaxf(a2.z, 0.f); a2.w = fmaxf(a2.w, 0.f);
    a3.x = fmaxf(a3.x, 0.f); a3.y = fmaxf(a3.y, 0.f); a3.z = fmaxf(a3.z, 0.f); a3.w = fmaxf(a3.w, 0.f);
    uint4 p0, p1;
    p0.x = f2bf(a0.x) | (f2bf(a0.y) << 16);
    p0.y = f2bf(a0.z) | (f2bf(a0.w) << 16);
    p0.z = f2bf(a1.x) | (f2bf(a1.y) << 16);
    p0.w = f2bf(a1.z) | (f2bf(a1.w) << 16);
    p1.x = f2bf(a2.x) | (f2bf(a2.y) << 16);
    p1.y = f2bf(a2.z) | (f2bf(a2.w) << 16);
    p1.z = f2bf(a3.x) | (f2bf(a3.y) << 16);
    p1.w = f2bf(a3.z) | (f2bf(a3.w) << 16);
    uint4* outp = (uint4*)X2b + (size_t)n * 8 + (tid & 3) * 2;
    outp[0] = p0; outp[1] = p1;
}

// ---------------------------------------------------------------------------
// K_rp: one-shot repack of Qw into W2[64][128] = [A|B] row-major.
// ---------------------------------------------------------------------------
__global__ __launch_bounds__(256) void k_repackB(const float* __restrict__ Qw,
                                                 float* __restrict__ W2) {
    int i = blockIdx.x * 256 + threadIdx.x;   // grid covers 8192
    if (i >= 8192) return;
    int f = i >> 7, c = i & 127;
    float v;
    if (c < 64) v = Qw[(c >> 4) * 2048 + f * 16 + (c & 15)];
    else { int cc = c - 64; v = Qw[(cc >> 4) * 2048 + (64 + f) * 16 + (cc & 15)]; }
    W2[i] = v;
}

// ---------------------------------------------------------------------------
// K5b: [a|b] = X2 · W2 (+[Qb|0]). W2 in LDS with PADDED-GROUP layout:
// row f = 8 groups of (16 data + 4 pad) floats -> stride 160; part p's base
// bank = (p*20)%32 = {0,20,8,28,16,4,24,12} -> the 8 lanes' float4s tile all
// 32 banks, ZERO conflict (round-12 profile: 12.8M conflicts with the old
// dense layout). 8 threads/node; bf16 in, bf16 out [N][64].
// ---------------------------------------------------------------------------
__global__ __launch_bounds__(256) void k_phaseB(const unsigned* __restrict__ X2b,
                                                const float* __restrict__ W2,
                                                const float* __restrict__ Qb,
                                                unsigned* __restrict__ aOut,
                                                unsigned* __restrict__ bOut, int N) {
    __shared__ float sW[10240];              // 64 rows x 160 floats = 40KB
    int tid = threadIdx.x;
    for (int i = tid; i < 8192; i += 256) {
        int f = i >> 7, c = i & 127;
        sW[f * 160 + (c >> 4) * 20 + (c & 15)] = W2[i];
    }
    __syncthreads();

    int n = blockIdx.x * 32 + (tid >> 3);
    if (n >= N) return;
    int part = tid & 7;                 // 0..3 -> a cols, 4..7 -> b cols
    const float4* w4 = (const float4*)sW;    // row f -> w4[f*40 + part*5 + k]
    float4 a0, a1, a2, a3;
    if (part < 4) {
        const float4* qv = (const float4*)Qb;
        int wb = part << 2;
        a0 = qv[wb]; a1 = qv[wb + 1]; a2 = qv[wb + 2]; a3 = qv[wb + 3];
    } else {
        a0 = a1 = a2 = a3 = make_float4(0.f, 0.f, 0.f, 0.f);
    }
    const uint4* Xv = (const uint4*)X2b + (size_t)n * 8;
    int pbase = part * 5;
    #pragma unroll 2
    for (int q8 = 0; q8 < 8; ++q8) {
        uint4 xu = Xv[q8];
        float xs[8] = {bf_lo(xu.x), bf_hi(xu.x), bf_lo(xu.y), bf_hi(xu.y),
                       bf_lo(xu.z), bf_hi(xu.z), bf_lo(xu.w), bf_hi(xu.w)};
        #pragma unroll
        for (int j = 0; j < 8; ++j) {
            int b4 = (8 * q8 + j) * 40 + pbase;
            float4 w0 = w4[b4], w1 = w4[b4 + 1], w2 = w4[b4 + 2], w3 = w4[b4 + 3];
            float xj = xs[j];
            a0.x += xj * w0.x; a0.y += xj * w0.y; a0.z += xj * w0.z; a0.w += xj * w0.w;
            a1.x += xj * w1.x; a1.y += xj * w1.y; a1.z += xj * w1.z; a1.w += xj * w1.w;
            a2.x += xj * w2.x; a2.y += xj * w2.y; a2.z += xj * w2.z; a2.w += xj * w2.w;
            a3.x += xj * w3.x; a3.y += xj * w3.y; a3.z += xj * w3.z; a3.w += xj * w3.w;
        }
    }
    uint4 p0, p1;
    p0.x = f2bf(a0.x) | (f2bf(a0.y) << 16);
    p0.y = f2bf(a0.z) | (f2bf(a0.w) << 16);
    p0.z = f2bf(a1.x) | (f2bf(a1.y) << 16);
    p0.w = f2bf(a1.z) | (f2bf(a1.w) << 16);
    p1.x = f2bf(a2.x) | (f2bf(a2.y) << 16);
    p1.y = f2bf(a2.z) | (f2bf(a2.w) << 16);
    p1.z = f2bf(a3.x) | (f2bf(a3.y) << 16);
    p1.w = f2bf(a3.z) | (f2bf(a3.w) << 16);
    uint4* outp = (part < 4) ? (uint4*)aOut + (size_t)n * 8 + part * 2
                             : (uint4*)bOut + (size_t)n * 8 + (part - 4) * 2;
    outp[0] = p0; outp[1] = p1;
}

// ---------------------------------------------------------------------------
// K6: gg[n,:] = tanh(mean over out-edges of (a[n,:] + b[dst,:])^2)
// a and b both bf16 rows [N][64]; 32 edges/iter = 4 loads in flight.
// ---------------------------------------------------------------------------
#define FIN_ACC(u) { float t; \
    t = avA.x + bf_lo(u.x); accA.x += t * t; \
    t = avA.y + bf_hi(u.x); accA.y += t * t; \
    t = avA.z + bf_lo(u.y); accA.z += t * t; \
    t = avA.w + bf_hi(u.y); accA.w += t * t; \
    t = avB.x + bf_lo(u.z); accB.x += t * t; \
    t = avB.y + bf_hi(u.z); accB.y += t * t; \
    t = avB.z + bf_lo(u.w); accB.z += t * t; \
    t = avB.w + bf_hi(u.w); accB.w += t * t; }
#define FIN_ACCM(u, f) { float t; \
    t = avA.x + bf_lo(u.x); accA.x += f * t * t; \
    t = avA.y + bf_hi(u.x); accA.y += f * t * t; \
    t = avA.z + bf_lo(u.y); accA.z += f * t * t; \
    t = avA.w + bf_hi(u.y); accA.w += f * t * t; \
    t = avB.x + bf_lo(u.z); accB.x += f * t * t; \
    t = avB.y + bf_hi(u.z); accB.y += f * t * t; \
    t = avB.z + bf_lo(u.w); accB.z += f * t * t; \
    t = avB.w + bf_hi(u.w); accB.w += f * t * t; }

__global__ __launch_bounds__(256) void k_final(const unsigned* __restrict__ aFb,
                                               const unsigned* __restrict__ bFb,
                                               const int* __restrict__ off_src,
                                               const int* __restrict__ csr_src,
                                               float* __restrict__ out, int N) {
    int lane = threadIdx.x & 63;
    int node = blockIdx.x * 4 + (threadIdx.x >> 6);
    if (node >= N) return;
    int grp = lane >> 3, col8 = lane & 7;
    const uint4* Bv = (const uint4*)bFb;
    uint4 au = ((const uint4*)aFb)[(size_t)node * 8 + col8];
    float4 avA = make_float4(bf_lo(au.x), bf_hi(au.x), bf_lo(au.y), bf_hi(au.y));
    float4 avB = make_float4(bf_lo(au.z), bf_hi(au.z), bf_lo(au.w), bf_hi(au.w));
    int s0 = off_src[node], s1 = off_src[node + 1];
    float4 accA = make_float4(0.f, 0.f, 0.f, 0.f);
    float4 accB = make_float4(0.f, 0.f, 0.f, 0.f);
    for (int base = s0; base < s1; base += 64) {
        int cnt = min(64, s1 - base);
        int idx = (base + lane < s1) ? csr_src[base + lane] : 0;
        int j = 0;
        for (; j + 32 <= cnt; j += 32) {
            int m0 = __shfl(idx, j + grp);
            int m1 = __shfl(idx, j + 8 + grp);
            int m2 = __shfl(idx, j + 16 + grp);
            int m3 = __shfl(idx, j + 24 + grp);
            uint4 u0 = Bv[(size_t)m0 * 8 + col8];
            uint4 u1 = Bv[(size_t)m1 * 8 + col8];
            uint4 u2 = Bv[(size_t)m2 * 8 + col8];
            uint4 u3 = Bv[(size_t)m3 * 8 + col8];
            FIN_ACC(u0); FIN_ACC(u1); FIN_ACC(u2); FIN_ACC(u3);
        }
        if (j < cnt) {
            int q0 = j + grp, q1 = j + 8 + grp, q2 = j + 16 + grp, q3 = j + 24 + grp;
            int m0 = __shfl(idx, q0);
            int m1 = __shfl(idx, q1);
            int m2 = __shfl(idx, q2);
            int m3 = __shfl(idx, q3);
            float f0 = (q0 < cnt) ? 1.f : 0.f; if (q0 >= cnt) m0 = 0;
            float f1 = (q1 < cnt) ? 1.f : 0.f; if (q1 >= cnt) m1 = 0;
            float f2 = (q2 < cnt) ? 1.f : 0.f; if (q2 >= cnt) m2 = 0;
            float f3 = (q3 < cnt) ? 1.f : 0.f; if (q3 >= cnt) m3 = 0;
            uint4 u0 = Bv[(size_t)m0 * 8 + col8];
            uint4 u1 = Bv[(size_t)m1 * 8 + col8];
            uint4 u2 = Bv[(size_t)m2 * 8 + col8];
            uint4 u3 = Bv[(size_t)m3 * 8 + col8];
            FIN_ACCM(u0, f0); FIN_ACCM(u1, f1); FIN_ACCM(u2, f2); FIN_ACCM(u3, f3);
        }
    }
    #pragma unroll
    for (int d = 8; d < 64; d <<= 1) {
        accA.x += __shfl_xor(accA.x, d); accA.y += __shfl_xor(accA.y, d);
        accA.z += __shfl_xor(accA.z, d); accA.w += __shfl_xor(accA.w, d);
        accB.x += __shfl_xor(accB.x, d); accB.y += __shfl_xor(accB.y, d);
        accB.z += __shfl_xor(accB.z, d); accB.w += __shfl_xor(accB.w, d);
    }
    if (grp == 0) {
        int deg = s1 - s0;
        float inv = 1.f / (float)max(deg, 1);
        float4 r0 = make_float4(tanhf(accA.x * inv), tanhf(accA.y * inv),
                                tanhf(accA.z * inv), tanhf(accA.w * inv));
        float4 r1 = make_float4(tanhf(accB.x * inv), tanhf(accB.y * inv),
                                tanhf(accB.z * inv), tanhf(accB.w * inv));
        ((float4*)out)[(size_t)node * 16 + col8 * 2]     = r0;
        ((float4*)out)[(size_t)node * 16 + col8 * 2 + 1] = r1;
    }
}

// ---------------------------------------------------------------------------
extern "C" void kernel_launch(void* const* d_in, const int* in_sizes, int n_in,
                              void* d_out, int out_size, void* d_ws, size_t ws_size,
                              hipStream_t stream) {
    const float* X      = (const float*)d_in[0];
    const int*   ei     = (const int*)d_in[1];
    const float* Wself  = (const float*)d_in[2];
    const float* Wneigh = (const float*)d_in[3];
    const float* bconv  = (const float*)d_in[4];
    const float* Qw     = (const float*)d_in[5];
    const float* Qb     = (const float*)d_in[6];

    int N = in_sizes[0] / NHID;
    int E = in_sizes[1] / 2;
    const int* src = ei;        // edge_index[0]
    const int* dst = ei + E;    // edge_index[1]
    int nB = (N + NPB - 1) >> NPB_SHIFT;           // 196 for N=100K
    int nChunks = (E + CHUNK - 1) / CHUNK;         // 391 for E=3.2M

    // ---- workspace layout (~103 MB) ----
    char* ws = (char*)d_ws;
    size_t bufBytes = (size_t)MAXB * CAP * 4;      // 21.0 MB per side
    size_t NH4 = (size_t)N * NHID * 4;             // 25.6 MB
    size_t NH2 = (size_t)N * NHID * 2;             // 12.8 MB
    unsigned int* buf0 = (unsigned int*)(ws);
    unsigned int* buf1 = (unsigned int*)(ws + bufBytes);
    float*    aggF = (float*)(ws);                              // [0, 25.6)
    unsigned* X2b  = (unsigned*)(ws + NH4);                     // [25.6, 38.4)
    unsigned* aFb  = (unsigned*)(ws + NH4 + NH2);               // [38.4, 51.2)
    unsigned* bFb  = (unsigned*)(ws + NH4 + 2 * NH2);           // [51.2, 64.0)
    unsigned* Xb   = (unsigned*)(ws + NH4 + 3 * NH2);           // [64.0, 76.8)
    size_t pos = NH4 + 4 * NH2;                                 // 76.8 MB
    if (pos < 2 * bufBytes) pos = 2 * bufBytes;
    pos = (pos + 255) & ~(size_t)255;
    auto alloc = [&](size_t bytes) -> void* {
        void* p = ws + pos;
        pos = (pos + bytes + 255) & ~(size_t)255;
        return p;
    };
    int* csr0   = (int*)alloc((size_t)E * 4);      // by dst
    int* csr1   = (int*)alloc((size_t)E * 4);      // by src
    int* off0   = (int*)alloc((size_t)(N + 1) * 4);
    int* off1   = (int*)alloc((size_t)(N + 1) * 4);
    int* btail0 = (int*)alloc((size_t)MAXB * 4);
    int* btail1 = (int*)alloc((size_t)MAXB * 4);
    int* boff0  = (int*)alloc((size_t)MAXB * 4);
    int* boff1  = (int*)alloc((size_t)MAXB * 4);
    float* W2   = (float*)alloc((size_t)8192 * 4); // repacked [A|B], 32KB
    (void)ws_size; (void)n_in; (void)out_size;

    hipMemsetAsync(btail0, 0, (size_t)2 * MAXB * 4, stream);   // btail0+btail1 contiguous

    k_bucketA<<<nChunks * 2, 256, 0, stream>>>(src, dst, buf0, buf1, btail0, btail1, E, nB);
    k_bscan<<<1, 256, 0, stream>>>(btail0, btail1, boff0, boff1, off0, off1, nB, N);
    k_repackB<<<32, 256, 0, stream>>>(Qw, W2);
    k_xcast<<<(N * 8 + 255) / 256, 256, 0, stream>>>(X, Xb, N * 8);
    k_bucket_csr<<<nB * 2, 512, 0, stream>>>(buf0, buf1, btail0, btail1,
                                             boff0, boff1, off0, off1, csr0, csr1, N);
    k_agg<<<(N + 3) / 4, 256, 0, stream>>>(Xb, off0, csr0, aggF, N);
    k_phaseA<<<(N + 63) / 64, 256, 0, stream>>>(X, aggF, Wself, Wneigh, bconv, X2b, N);
    k_phaseB<<<(N + 31) / 32, 256, 0, stream>>>(X2b, W2, Qb, aFb, bFb, N);
    k_final<<<(N + 3) / 4, 256, 0, stream>>>(aFb, bFb, off1, csr1, (float*)d_out, N);
}